// Round 9
// baseline (570.963 us; speedup 1.0000x reference)
//
#include <hip/hip_runtime.h>

// RGCN: 2-layer, R=4, N=100000, E=500000/rel, 128->128->64.
// Round 9: B-operands direct from global (no B LDS staging); paired-edge
// gathers (2 edges/wave-instruction, cross-half shfl combine); phase-1
// mega-kernel hides layer-1 GEMM under the atomic-bound degree count.

constexpr int Nn  = 100000;
constexpr int Rr  = 4;
constexpr int Ee  = 500000;
constexpr int RE  = Rr * Ee;
constexpr int TOT = Rr * Nn;
constexpr int NP  = 100096;            // Nn padded to 128 rows
constexpr int NPB = NP / 128;          // 782 row-blocks
constexpr int NB1 = 1024;
constexpr int CH  = (TOT + NB1 - 1) / NB1;

// phase-1 grid decode: count || gemm1 || bsum
constexpr int CB    = (RE + 255) / 256;             // 7813 count blocks
constexpr int GB1   = 4 * NPB;                      // 3128 gemm blocks
constexpr int PAIR1 = 2 * GB1;                      // interleaved region
constexpr int P1_GRID = PAIR1 + (CB - GB1) + 1;

constexpr int FB = (RE / 4 + 255) / 256;            // fill blocks

typedef short bf16x8 __attribute__((ext_vector_type(8)));
typedef float f32x4  __attribute__((ext_vector_type(4)));

__device__ __forceinline__ unsigned short f2bf(float f) {
    unsigned u = __builtin_bit_cast(unsigned, f);
    u = u + 0x7FFFu + ((u >> 16) & 1u);          // round-to-nearest-even
    return (unsigned short)(u >> 16);
}
__device__ __forceinline__ float bf2f(unsigned short h) {
    unsigned u = ((unsigned)h) << 16;
    return __builtin_bit_cast(float, u);
}
__device__ __forceinline__ float bfbits_lo(unsigned p) {
    return __builtin_bit_cast(float, p << 16);
}
__device__ __forceinline__ float bfbits_hi(unsigned p) {
    return __builtin_bit_cast(float, p & 0xFFFF0000u);
}

// ---------------- role bodies ----------------
__device__ __forceinline__ void count_body(int sub, int tid,
    const int* __restrict__ src, const int* __restrict__ dst,
    unsigned* __restrict__ deg, unsigned* __restrict__ slot)
{
    int e = sub * 256 + tid;
    if (e >= RE) return;
    int r = (unsigned)e / (unsigned)Ee;
    int base = r * Nn;
    atomicAdd(&deg[base + src[e]], 1u);                     // fire-and-forget
    slot[e] = atomicAdd(&deg[TOT + base + dst[e]], 1u);     // rank in segment
}

__device__ __forceinline__ void bsum_body(int tid,
    const float* __restrict__ b1, const float* __restrict__ b2,
    float* __restrict__ bs1, float* __restrict__ bs2)
{
    if (tid < 128) bs1[tid] = b1[tid] + b1[128 + tid] + b1[256 + tid] + b1[384 + tid];
    if (tid < 64)  bs2[tid] = b2[tid] + b2[64 + tid] + b2[128 + tid] + b2[192 + tid];
}

// ---------------- GEMM body: A in LDS (hi/lo), B direct from global ----------------
template<int BN, bool CONVA>
__device__ __forceinline__ void gemm_body(
    const short* __restrict__ Xh, const short* __restrict__ Xl,
    const float* __restrict__ Xf,
    const short* __restrict__ WhT_, const short* __restrict__ WlT_,
    short* __restrict__ Y_, int CW, int rowblk, int rel)
{
    constexpr int BM = 128, BKp = 40;            // 32 k + 8 pad
    constexpr int MFR = (BN == 128) ? 4 : 2;
    constexpr int NFR = 4;
    const short* WhT = WhT_ + (size_t)rel * (BN * 128);
    const short* WlT = WlT_ + (size_t)rel * (BN * 128);
    short* Y = Y_ + (size_t)rel * BN;

    __shared__ __align__(16) short Ah[BM * BKp], Al[BM * BKp];

    const int tid = threadIdx.x;
    const int lane = tid & 63, wid = tid >> 6;
    const int lr = lane & 15, lg = lane >> 4;
    const int wm0 = (BN == 128) ? (wid >> 1) * 64 : wid * 32;
    const int wn0 = (BN == 128) ? (wid & 1) * 64 : 0;
    const int row0 = rowblk * BM;

    f32x4 acc[MFR][NFR];
    #pragma unroll
    for (int m = 0; m < MFR; ++m)
        #pragma unroll
        for (int n = 0; n < NFR; ++n)
            #pragma unroll
            for (int j = 0; j < 4; ++j) acc[m][n][j] = 0.f;

    const int sr = tid >> 1;
    const int sko = (tid & 1) * 16;

    for (int ks = 0; ks < 4; ++ks) {
        if constexpr (CONVA) {
            int grow = row0 + sr;
            float v[16];
            if (grow < Nn) {
                const float* xp = Xf + (size_t)grow * 128 + ks * 32 + sko;
                float4 a0 = *reinterpret_cast<const float4*>(xp);
                float4 a1 = *reinterpret_cast<const float4*>(xp + 4);
                float4 a2 = *reinterpret_cast<const float4*>(xp + 8);
                float4 a3 = *reinterpret_cast<const float4*>(xp + 12);
                v[0]=a0.x; v[1]=a0.y; v[2]=a0.z; v[3]=a0.w;
                v[4]=a1.x; v[5]=a1.y; v[6]=a1.z; v[7]=a1.w;
                v[8]=a2.x; v[9]=a2.y; v[10]=a2.z; v[11]=a2.w;
                v[12]=a3.x; v[13]=a3.y; v[14]=a3.z; v[15]=a3.w;
            } else {
                #pragma unroll
                for (int i = 0; i < 16; ++i) v[i] = 0.f;
            }
            bf16x8 h0, h1, l0, l1;
            #pragma unroll
            for (int i = 0; i < 8; ++i) {
                unsigned short h = f2bf(v[i]);
                h0[i] = (short)h; l0[i] = (short)f2bf(v[i] - bf2f(h));
                unsigned short g = f2bf(v[8 + i]);
                h1[i] = (short)g; l1[i] = (short)f2bf(v[8 + i] - bf2f(g));
            }
            *reinterpret_cast<bf16x8*>(&Ah[sr * BKp + sko])     = h0;
            *reinterpret_cast<bf16x8*>(&Ah[sr * BKp + sko + 8]) = h1;
            *reinterpret_cast<bf16x8*>(&Al[sr * BKp + sko])     = l0;
            *reinterpret_cast<bf16x8*>(&Al[sr * BKp + sko + 8]) = l1;
        } else {
            size_t ga = (size_t)(row0 + sr) * 128 + ks * 32 + sko;
            *reinterpret_cast<bf16x8*>(&Ah[sr * BKp + sko])     = *reinterpret_cast<const bf16x8*>(&Xh[ga]);
            *reinterpret_cast<bf16x8*>(&Ah[sr * BKp + sko + 8]) = *reinterpret_cast<const bf16x8*>(&Xh[ga + 8]);
            *reinterpret_cast<bf16x8*>(&Al[sr * BKp + sko])     = *reinterpret_cast<const bf16x8*>(&Xl[ga]);
            *reinterpret_cast<bf16x8*>(&Al[sr * BKp + sko + 8]) = *reinterpret_cast<const bf16x8*>(&Xl[ga + 8]);
        }
        __syncthreads();

        // B fragments straight from global (weights are L2-hot, reused by all blocks)
        bf16x8 bh[NFR], bl[NFR];
        #pragma unroll
        for (int n = 0; n < NFR; ++n) {
            size_t bo = (size_t)(wn0 + n * 16 + lr) * 128 + ks * 32 + lg * 8;
            bh[n] = *reinterpret_cast<const bf16x8*>(WhT + bo);
            bl[n] = *reinterpret_cast<const bf16x8*>(WlT + bo);
        }
        #pragma unroll
        for (int m = 0; m < MFR; ++m) {
            bf16x8 ah = *reinterpret_cast<const bf16x8*>(&Ah[(wm0 + m * 16 + lr) * BKp + lg * 8]);
            bf16x8 al = *reinterpret_cast<const bf16x8*>(&Al[(wm0 + m * 16 + lr) * BKp + lg * 8]);
            #pragma unroll
            for (int n = 0; n < NFR; ++n) {
                acc[m][n] = __builtin_amdgcn_mfma_f32_16x16x32_bf16(ah, bh[n], acc[m][n], 0, 0, 0);
                acc[m][n] = __builtin_amdgcn_mfma_f32_16x16x32_bf16(ah, bl[n], acc[m][n], 0, 0, 0);
                acc[m][n] = __builtin_amdgcn_mfma_f32_16x16x32_bf16(al, bh[n], acc[m][n], 0, 0, 0);
            }
        }
        __syncthreads();
    }

    // C/D layout: col=lane&15, row=(lane>>4)*4+j  [m89]
    #pragma unroll
    for (int m = 0; m < MFR; ++m)
        #pragma unroll
        for (int n = 0; n < NFR; ++n) {
            int col = wn0 + n * 16 + lr;
            int rb = row0 + wm0 + m * 16 + lg * 4;
            #pragma unroll
            for (int j = 0; j < 4; ++j)
                Y[(size_t)(rb + j) * CW + col] = (short)f2bf(acc[m][n][j]);
        }
}

// ---------------- phase 1: count || gemm1(4 rel, inline conv) || bsum ----------------
__global__ __launch_bounds__(256)
void phase1_kernel(const int* __restrict__ src, const int* __restrict__ dst,
                   unsigned* __restrict__ deg, unsigned* __restrict__ slot,
                   const float* __restrict__ X,
                   const short* __restrict__ w1h, const short* __restrict__ w1l,
                   short* __restrict__ Y,
                   const float* __restrict__ b1, const float* __restrict__ b2,
                   float* __restrict__ bs1, float* __restrict__ bs2)
{
    int bid = blockIdx.x, tid = threadIdx.x;
    if (bid < PAIR1) {
        int sub = bid >> 1;
        if (bid & 1) {
            int rel = sub & 3, rowblk = sub >> 2;
            gemm_body<128, true>(nullptr, nullptr, X, w1h, w1l, Y, 512, rowblk, rel);
        } else {
            count_body(sub, tid, src, dst, deg, slot);
        }
    } else {
        int t = bid - PAIR1;
        if (t < CB - GB1) count_body(GB1 + t, tid, src, dst, deg, slot);
        else              bsum_body(tid, b1, b2, bs1, bs2);
    }
}

// standalone count / bsum (path B)
__global__ __launch_bounds__(256)
void count_kernel(const int* __restrict__ src, const int* __restrict__ dst,
                  unsigned* __restrict__ deg, unsigned* __restrict__ slot)
{
    count_body(blockIdx.x, threadIdx.x, src, dst, deg, slot);
}

__global__ void bsum_kernel(const float* __restrict__ b1, const float* __restrict__ b2,
                            float* __restrict__ bs1, float* __restrict__ bs2)
{
    bsum_body(threadIdx.x, b1, b2, bs1, bs2);
}

// norms; stash ndst bits into packed rpnd
__global__ __launch_bounds__(256)
void norms_kernel(const unsigned* __restrict__ deg, float* __restrict__ nrm,
                  uint2* __restrict__ rpnd)
{
    int gid = blockIdx.x * 256 + threadIdx.x;
    if (gid >= TOT) return;
    unsigned s = deg[gid], d = deg[TOT + gid];
    nrm[gid] = rsqrtf((float)(s > 0u ? s : 1u));
    rpnd[gid].y = __builtin_bit_cast(unsigned, rsqrtf((float)(d > 0u ? d : 1u)));
}

__global__ __launch_bounds__(256)
void scan1_kernel(const unsigned* __restrict__ deg, unsigned* __restrict__ partial)
{
    __shared__ unsigned s[256];
    int b = blockIdx.x, t = threadIdx.x;
    int start = b * CH;
    int n = TOT - start; if (n > CH) n = CH;
    unsigned sum = 0;
    for (int i = t; i < n; i += 256) sum += deg[TOT + start + i];
    s[t] = sum; __syncthreads();
    for (int d = 128; d > 0; d >>= 1) {
        if (t < d) s[t] += s[t + d];
        __syncthreads();
    }
    if (t == 0) partial[b] = s[0];
}

__global__ __launch_bounds__(1024)
void scan2_kernel(unsigned* __restrict__ partial, unsigned* __restrict__ rowptr)
{
    __shared__ unsigned s[NB1];
    int t = threadIdx.x;
    unsigned orig = partial[t];
    s[t] = orig; __syncthreads();
    for (int d = 1; d < NB1; d <<= 1) {
        unsigned v = (t >= d) ? s[t - d] : 0u;
        __syncthreads();
        s[t] += v;
        __syncthreads();
    }
    partial[t] = s[t] - orig;
    if (t == 0) rowptr[TOT] = (unsigned)RE;
}

__global__ __launch_bounds__(256)
void scan3_kernel(const unsigned* __restrict__ deg, const unsigned* __restrict__ base,
                  unsigned* __restrict__ rowptr, uint2* __restrict__ rpnd)
{
    __shared__ unsigned s[CH];
    int b = blockIdx.x, t = threadIdx.x;
    int start = b * CH;
    int n = TOT - start; if (n > CH) n = CH;
    if (n <= 0) return;
    for (int i = t; i < n; i += 256) s[i] = deg[TOT + start + i];
    __syncthreads();
    if (t == 0) {
        unsigned run = base[b];
        for (int i = 0; i < n; ++i) { unsigned v = s[i]; s[i] = run; run += v; }
    }
    __syncthreads();
    for (int i = t; i < n; i += 256) {
        unsigned v = s[i];
        rowptr[start + i] = v;
        rpnd[start + i].x = v;
    }
}

// atomic-free CSR fill: pos = rowptr + slot (4 edges/thread)
__global__ __launch_bounds__(256)
void fill_csr_kernel(const int* __restrict__ src, const int* __restrict__ dst,
                     const unsigned* __restrict__ slot, const uint2* __restrict__ rpnd,
                     const float* __restrict__ nrm, int2* __restrict__ csrw)
{
    int e0 = (blockIdx.x * 256 + threadIdx.x) * 4;
    if (e0 >= RE) return;
    int r = (unsigned)e0 / (unsigned)Ee;
    int base = r * Nn;
    int4 s4 = *reinterpret_cast<const int4*>(src + e0);
    int4 d4 = *reinterpret_cast<const int4*>(dst + e0);
    uint4 sl = *reinterpret_cast<const uint4*>(slot + e0);
    #pragma unroll
    for (int i = 0; i < 4; ++i) {
        int s = (i == 0) ? s4.x : (i == 1) ? s4.y : (i == 2) ? s4.z : s4.w;
        int d = (i == 0) ? d4.x : (i == 1) ? d4.y : (i == 2) ? d4.z : d4.w;
        unsigned k = (i == 0) ? sl.x : (i == 1) ? sl.y : (i == 2) ? sl.z : sl.w;
        uint2 rn = rpnd[base + d];
        float w = nrm[base + s] * __builtin_bit_cast(float, rn.y);
        int2 v; v.x = s; v.y = __builtin_bit_cast(int, w);
        csrw[rn.x + k] = v;
    }
}

// convert W1/W2 to transposed hi/lo bf16
__global__ __launch_bounds__(256)
void convw_kernel(const float* __restrict__ W1, const float* __restrict__ W2,
                  short* __restrict__ w1h, short* __restrict__ w1l,
                  short* __restrict__ w2h, short* __restrict__ w2l)
{
    int gid = blockIdx.x * 256 + threadIdx.x;
    if (gid < 4 * 128 * 128) {
        int r = gid >> 14, rem = gid & 16383, n = rem >> 7, k = rem & 127;
        float v = W1[(r << 14) + k * 128 + n];
        unsigned short h = f2bf(v);
        unsigned short l = f2bf(v - bf2f(h));
        w1h[(r << 14) + n * 128 + k] = (short)h;
        w1l[(r << 14) + n * 128 + k] = (short)l;
    } else {
        int g2 = gid - 65536;
        if (g2 >= 4 * 64 * 128) return;
        int r = g2 >> 13, rem = g2 & 8191, n = rem >> 7, k = rem & 127;
        float v = W2[(r << 13) + k * 64 + n];
        unsigned short h = f2bf(v);
        unsigned short l = f2bf(v - bf2f(h));
        w2h[(r << 13) + n * 128 + k] = (short)h;
        w2l[(r << 13) + n * 128 + k] = (short)l;
    }
}

// standalone GEMM: blockIdx.y = relation
template<int BN, bool CONVA>
__global__ __launch_bounds__(256)
void gemm_kernel(const short* __restrict__ Xh, const short* __restrict__ Xl,
                 const float* __restrict__ Xf,
                 const short* __restrict__ WhT_, const short* __restrict__ WlT_,
                 short* __restrict__ Y_, int CW)
{
    gemm_body<BN, CONVA>(Xh, Xl, Xf, WhT_, WlT_, Y_, CW, blockIdx.x, blockIdx.y);
}

// ---------------- paired-edge CSR gather over NR relations (Y bf16) ----------------
// Lanes 0-31 process even edges, 32-63 odd edges (same features); one
// cross-half shfl_xor combine at the end. FL = features per lane.
template<int F, int NR>
__global__ __launch_bounds__(256)
void gather_kernel(const short* __restrict__ Y, const unsigned* __restrict__ rowptr,
                   const int2* __restrict__ csrw, const float* __restrict__ bsum,
                   float* __restrict__ H, short* __restrict__ Xh, short* __restrict__ Xl,
                   int CW, int accumulate, int finalize)
{
    constexpr int FL = F / 32;               // 4 (F=128) or 2 (F=64)
    int wid = (blockIdx.x * 256 + threadIdx.x) >> 6;
    int lane = threadIdx.x & 63;
    int half = lane >> 5, li = lane & 31;
    if (wid >= Nn) return;

    float t[FL];
    #pragma unroll
    for (int f = 0; f < FL; ++f) t[f] = 0.f;

    #pragma unroll
    for (int rl = 0; rl < NR; ++rl) {
        const short* yr = Y + rl * F;
        unsigned e  = rowptr[rl * Nn + wid];
        unsigned e1 = rowptr[rl * Nn + wid + 1];
        // 2 pairs in flight (4 edges per iteration)
        for (; e + 4 <= e1; e += 4) {
            int2 a0 = csrw[e + half];
            int2 a1 = csrw[e + 2 + half];
            float w0 = __builtin_bit_cast(float, a0.y);
            float w1 = __builtin_bit_cast(float, a1.y);
            if constexpr (FL == 4) {
                uint2 p0 = *reinterpret_cast<const uint2*>(yr + (size_t)a0.x * CW + li * 4);
                uint2 p1 = *reinterpret_cast<const uint2*>(yr + (size_t)a1.x * CW + li * 4);
                t[0] += w0 * bfbits_lo(p0.x) + w1 * bfbits_lo(p1.x);
                t[1] += w0 * bfbits_hi(p0.x) + w1 * bfbits_hi(p1.x);
                t[2] += w0 * bfbits_lo(p0.y) + w1 * bfbits_lo(p1.y);
                t[3] += w0 * bfbits_hi(p0.y) + w1 * bfbits_hi(p1.y);
            } else {
                unsigned p0 = *reinterpret_cast<const unsigned*>(yr + (size_t)a0.x * CW + li * 2);
                unsigned p1 = *reinterpret_cast<const unsigned*>(yr + (size_t)a1.x * CW + li * 2);
                t[0] += w0 * bfbits_lo(p0) + w1 * bfbits_lo(p1);
                t[1] += w0 * bfbits_hi(p0) + w1 * bfbits_hi(p1);
            }
        }
        // one pair
        if (e + 2 <= e1) {
            int2 a = csrw[e + half];
            float w = __builtin_bit_cast(float, a.y);
            if constexpr (FL == 4) {
                uint2 p = *reinterpret_cast<const uint2*>(yr + (size_t)a.x * CW + li * 4);
                t[0] += w * bfbits_lo(p.x); t[1] += w * bfbits_hi(p.x);
                t[2] += w * bfbits_lo(p.y); t[3] += w * bfbits_hi(p.y);
            } else {
                unsigned p = *reinterpret_cast<const unsigned*>(yr + (size_t)a.x * CW + li * 2);
                t[0] += w * bfbits_lo(p); t[1] += w * bfbits_hi(p);
            }
            e += 2;
        }
        // single tail edge: half 0 only
        if (e < e1 && half == 0) {
            int2 a = csrw[e];
            float w = __builtin_bit_cast(float, a.y);
            if constexpr (FL == 4) {
                uint2 p = *reinterpret_cast<const uint2*>(yr + (size_t)a.x * CW + li * 4);
                t[0] += w * bfbits_lo(p.x); t[1] += w * bfbits_hi(p.x);
                t[2] += w * bfbits_lo(p.y); t[3] += w * bfbits_hi(p.y);
            } else {
                unsigned p = *reinterpret_cast<const unsigned*>(yr + (size_t)a.x * CW + li * 2);
                t[0] += w * bfbits_lo(p); t[1] += w * bfbits_hi(p);
            }
        }
    }

    // cross-half combine
    #pragma unroll
    for (int f = 0; f < FL; ++f) t[f] += __shfl_xor(t[f], 32, 64);

    if (half != 0) return;
    float* hp = H + (size_t)wid * F + li * FL;
    if (accumulate) {
        #pragma unroll
        for (int f = 0; f < FL; ++f) t[f] += hp[f];
    } else {
        #pragma unroll
        for (int f = 0; f < FL; ++f) t[f] += bsum[li * FL + f];
    }
    if (F == 128 && finalize) {
        short4 hv, lv;
        #pragma unroll
        for (int f = 0; f < 4; ++f) {
            float v = fmaxf(t[f], 0.f);
            unsigned short hb = f2bf(v);
            ((short*)&hv)[f] = (short)hb;
            ((short*)&lv)[f] = (short)f2bf(v - bf2f(hb));
        }
        *reinterpret_cast<short4*>(Xh + (size_t)wid * F + li * 4) = hv;
        *reinterpret_cast<short4*>(Xl + (size_t)wid * F + li * 4) = lv;
    } else {
        if constexpr (FL == 4) {
            *reinterpret_cast<float4*>(hp) = make_float4(t[0], t[1], t[2], t[3]);
        } else {
            *reinterpret_cast<float2*>(hp) = make_float2(t[0], t[1]);
        }
    }
}

extern "C" void kernel_launch(void* const* d_in, const int* in_sizes, int n_in,
                              void* d_out, int out_size, void* d_ws, size_t ws_size,
                              hipStream_t stream)
{
    const float* x  = (const float*)d_in[0];
    const int* esrc = (const int*)d_in[1];
    const int* edst = (const int*)d_in[2];
    const float* W1 = (const float*)d_in[3];
    const float* b1 = (const float*)d_in[4];
    const float* W2 = (const float*)d_in[5];
    const float* b2 = (const float*)d_in[6];
    float* out = (float*)d_out;

    // ---- workspace layout ----
    char* ws = (char*)d_ws;
    size_t off = 0;
    auto alloc = [&](size_t bytes) { char* p = ws + off; off += (bytes + 255) & ~(size_t)255; return p; };
    unsigned* deg     = (unsigned*)alloc((size_t)2 * TOT * 4);
    float*    nrm     = (float*)   alloc((size_t)TOT * 4);          // nsrc
    uint2*    rpnd    = (uint2*)   alloc((size_t)TOT * 8);          // {rowptr, ndst}
    unsigned* rowptr  = (unsigned*)alloc((size_t)(TOT + 1) * 4);
    unsigned* partial = (unsigned*)alloc((size_t)NB1 * 4);
    unsigned* slot    = (unsigned*)alloc((size_t)RE * 4);
    float*    bs1     = (float*)   alloc(128 * 4);
    float*    bs2     = (float*)   alloc(64 * 4);
    short*    w1h     = (short*)   alloc((size_t)4 * 128 * 128 * 2);
    short*    w1l     = (short*)   alloc((size_t)4 * 128 * 128 * 2);
    short*    w2h     = (short*)   alloc((size_t)4 * 64 * 128 * 2);
    short*    w2l     = (short*)   alloc((size_t)4 * 64 * 128 * 2);
    int2*     csrw    = (int2*)    alloc((size_t)RE * 8);
    short*    xh      = (short*)   alloc((size_t)NP * 128 * 2);
    short*    xl      = (short*)   alloc((size_t)NP * 128 * 2);

    size_t yslot = (size_t)NP * 128 * 2;          // 25.6MB (bf16, 128 cols)
    bool pathA = (ws_size >= off + 4 * yslot + 4096);
    float* h = nullptr;
    short* Y;
    if (pathA) {
        Y = (short*)alloc(4 * yslot);
    } else {
        h = (float*)alloc((size_t)NP * 128 * 4);
        Y = (short*)alloc(yslot);
    }

    const int ggrid = (Nn * 64 + 255) / 256;      // one wave per dst node

    // ---- phase 0: weight conversion (tiny, independent) ----
    convw_kernel<<<384, 256, 0, stream>>>(W1, W2, w1h, w1l, w2h, w2l);
    hipMemsetAsync(deg, 0, (size_t)2 * TOT * 4, stream);

    if (pathA) {
        // ---- phase 1: count || gemm1(4 rel, inline x conv) || bsum ----
        phase1_kernel<<<P1_GRID, 256, 0, stream>>>(
            esrc, edst, deg, slot, x, w1h, w1l, Y, b1, b2, bs1, bs2);
        // ---- phase 2: norms + scan ----
        norms_kernel<<<(TOT + 255) / 256, 256, 0, stream>>>(deg, nrm, rpnd);
        scan1_kernel<<<NB1, 256, 0, stream>>>(deg, partial);
        scan2_kernel<<<1, NB1, 0, stream>>>(partial, rowptr);
        scan3_kernel<<<NB1, 256, 0, stream>>>(deg, partial, rowptr, rpnd);
        // ---- phase 3: fill ----
        fill_csr_kernel<<<FB, 256, 0, stream>>>(esrc, edst, slot, rpnd, nrm, csrw);
        // ---- phase 4: layer-1 gather (finalize: bias+ReLU+split into xh/xl) ----
        gather_kernel<128, 4><<<ggrid, 256, 0, stream>>>(
            Y, rowptr, csrw, bs1, out /*unused*/, xh, xl, 512, 0, 1);
        // ---- phase 5: layer-2 GEMM + gather ----
        gemm_kernel<64, false><<<dim3(NPB, 4), 256, 0, stream>>>(
            xh, xl, nullptr, w2h, w2l, Y, 256);
        gather_kernel<64, 4><<<ggrid, 256, 0, stream>>>(
            Y, rowptr, csrw, bs2, out, nullptr, nullptr, 256, 0, 0);
    } else {
        count_kernel<<<CB, 256, 0, stream>>>(esrc, edst, deg, slot);
        bsum_kernel<<<1, 128, 0, stream>>>(b1, b2, bs1, bs2);
        norms_kernel<<<(TOT + 255) / 256, 256, 0, stream>>>(deg, nrm, rpnd);
        scan1_kernel<<<NB1, 256, 0, stream>>>(deg, partial);
        scan2_kernel<<<1, NB1, 0, stream>>>(partial, rowptr);
        scan3_kernel<<<NB1, 256, 0, stream>>>(deg, partial, rowptr, rpnd);
        fill_csr_kernel<<<FB, 256, 0, stream>>>(esrc, edst, slot, rpnd, nrm, csrw);
        for (int r = 0; r < Rr; ++r) {
            gemm_kernel<128, true><<<dim3(NPB, 1), 256, 0, stream>>>(
                nullptr, nullptr, x, w1h + (size_t)r * 128 * 128, w1l + (size_t)r * 128 * 128, Y, 128);
            gather_kernel<128, 1><<<ggrid, 256, 0, stream>>>(
                Y, rowptr + (size_t)r * Nn, csrw, bs1, h, xh, xl, 128, r > 0, r == Rr - 1);
        }
        for (int r = 0; r < Rr; ++r) {
            gemm_kernel<64, false><<<dim3(NPB, 1), 256, 0, stream>>>(
                xh, xl, nullptr, w2h + (size_t)r * 64 * 128, w2l + (size_t)r * 64 * 128, Y, 64);
            gather_kernel<64, 1><<<ggrid, 256, 0, stream>>>(
                Y, rowptr + (size_t)r * Nn, csrw, bs2, out, nullptr, nullptr, 64, r > 0, 0);
        }
    }
}

// Round 10
// 499.590 us; speedup vs baseline: 1.1429x; 1.1429x over previous
//
#include <hip/hip_runtime.h>

// RGCN: 2-layer, R=4, N=100000, E=500000/rel, 128->128->64.
// Round 10: round-8 GEMM (A+B in LDS) + setprio(1) around MFMA (T5);
// 2-edge count threads (more atomic MLP at low occupancy); norms merged
// into scan1; paired-edge gathers; phase-1 hides layer-1 GEMM under count.

constexpr int Nn  = 100000;
constexpr int Rr  = 4;
constexpr int Ee  = 500000;
constexpr int RE  = Rr * Ee;
constexpr int TOT = Rr * Nn;
constexpr int NP  = 100096;            // Nn padded to 128 rows
constexpr int NPB = NP / 128;          // 782 row-blocks
constexpr int NB1 = 1024;
constexpr int CH  = (TOT + NB1 - 1) / NB1;

// phase-1 grid decode: count(2-edge) || gemm1 || bsum
constexpr int CB2   = (RE / 2 + 255) / 256;         // 3907 count blocks (2 edges/thread)
constexpr int GB1   = 4 * NPB;                      // 3128 gemm blocks
constexpr int PAIR1 = 2 * GB1;                      // 6256: gemm/count interleave
constexpr int P1_GRID = PAIR1 + (CB2 - GB1) + 1;    // + tail count + bsum

constexpr int FB = (RE / 4 + 255) / 256;            // fill blocks

typedef short bf16x8 __attribute__((ext_vector_type(8)));
typedef float f32x4  __attribute__((ext_vector_type(4)));

__device__ __forceinline__ unsigned short f2bf(float f) {
    unsigned u = __builtin_bit_cast(unsigned, f);
    u = u + 0x7FFFu + ((u >> 16) & 1u);          // round-to-nearest-even
    return (unsigned short)(u >> 16);
}
__device__ __forceinline__ float bf2f(unsigned short h) {
    unsigned u = ((unsigned)h) << 16;
    return __builtin_bit_cast(float, u);
}
__device__ __forceinline__ float bfbits_lo(unsigned p) {
    return __builtin_bit_cast(float, p << 16);
}
__device__ __forceinline__ float bfbits_hi(unsigned p) {
    return __builtin_bit_cast(float, p & 0xFFFF0000u);
}

// ---------------- role bodies ----------------
// deg: [2][TOT]; slot[e] = rank of edge within its (r,dst) segment.
// 2 edges per thread: int2 loads, 4 atomics in flight, uint2 slot store.
__device__ __forceinline__ void count_body2(int sub, int tid,
    const int* __restrict__ src, const int* __restrict__ dst,
    unsigned* __restrict__ deg, unsigned* __restrict__ slot)
{
    int e0 = (sub * 256 + tid) * 2;
    if (e0 >= RE) return;
    int r = (unsigned)e0 / (unsigned)Ee;          // Ee even -> pair same relation
    int base = r * Nn;
    int2 s2 = *reinterpret_cast<const int2*>(src + e0);
    int2 d2 = *reinterpret_cast<const int2*>(dst + e0);
    atomicAdd(&deg[base + s2.x], 1u);
    atomicAdd(&deg[base + s2.y], 1u);
    uint2 sl;
    sl.x = atomicAdd(&deg[TOT + base + d2.x], 1u);
    sl.y = atomicAdd(&deg[TOT + base + d2.y], 1u);
    *reinterpret_cast<uint2*>(slot + e0) = sl;
}

__device__ __forceinline__ void bsum_body(int tid,
    const float* __restrict__ b1, const float* __restrict__ b2,
    float* __restrict__ bs1, float* __restrict__ bs2)
{
    if (tid < 128) bs1[tid] = b1[tid] + b1[128 + tid] + b1[256 + tid] + b1[384 + tid];
    if (tid < 64)  bs2[tid] = b2[tid] + b2[64 + tid] + b2[128 + tid] + b2[192 + tid];
}

// ---------------- GEMM body (round-8: A+B in LDS, hi/lo split, bf16 out) ----------------
template<int BN, bool CONVA>
__device__ __forceinline__ void gemm_body(
    const short* __restrict__ Xh, const short* __restrict__ Xl,
    const float* __restrict__ Xf,
    const short* __restrict__ WhT_, const short* __restrict__ WlT_,
    short* __restrict__ Y_, int CW, int rowblk, int rel)
{
    constexpr int BM = 128, BKp = 40;            // 32 k + 8 pad
    constexpr int MFR = (BN == 128) ? 4 : 2;
    constexpr int NFR = 4;
    const short* WhT = WhT_ + (size_t)rel * (BN * 128);
    const short* WlT = WlT_ + (size_t)rel * (BN * 128);
    short* Y = Y_ + (size_t)rel * BN;

    __shared__ __align__(16) short Ah[BM * BKp], Al[BM * BKp];
    __shared__ __align__(16) short Bh[BN * BKp], Bl[BN * BKp];

    const int tid = threadIdx.x;
    const int lane = tid & 63, wid = tid >> 6;
    const int lr = lane & 15, lg = lane >> 4;
    const int wm0 = (BN == 128) ? (wid >> 1) * 64 : wid * 32;
    const int wn0 = (BN == 128) ? (wid & 1) * 64 : 0;
    const int row0 = rowblk * BM;

    f32x4 acc[MFR][NFR];
    #pragma unroll
    for (int m = 0; m < MFR; ++m)
        #pragma unroll
        for (int n = 0; n < NFR; ++n)
            #pragma unroll
            for (int j = 0; j < 4; ++j) acc[m][n][j] = 0.f;

    const int sr = tid >> 1;
    const int sko = (tid & 1) * 16;

    for (int ks = 0; ks < 4; ++ks) {
        if constexpr (CONVA) {
            int grow = row0 + sr;
            float v[16];
            if (grow < Nn) {
                const float* xp = Xf + (size_t)grow * 128 + ks * 32 + sko;
                float4 a0 = *reinterpret_cast<const float4*>(xp);
                float4 a1 = *reinterpret_cast<const float4*>(xp + 4);
                float4 a2 = *reinterpret_cast<const float4*>(xp + 8);
                float4 a3 = *reinterpret_cast<const float4*>(xp + 12);
                v[0]=a0.x; v[1]=a0.y; v[2]=a0.z; v[3]=a0.w;
                v[4]=a1.x; v[5]=a1.y; v[6]=a1.z; v[7]=a1.w;
                v[8]=a2.x; v[9]=a2.y; v[10]=a2.z; v[11]=a2.w;
                v[12]=a3.x; v[13]=a3.y; v[14]=a3.z; v[15]=a3.w;
            } else {
                #pragma unroll
                for (int i = 0; i < 16; ++i) v[i] = 0.f;
            }
            bf16x8 h0, h1, l0, l1;
            #pragma unroll
            for (int i = 0; i < 8; ++i) {
                unsigned short h = f2bf(v[i]);
                h0[i] = (short)h; l0[i] = (short)f2bf(v[i] - bf2f(h));
                unsigned short g = f2bf(v[8 + i]);
                h1[i] = (short)g; l1[i] = (short)f2bf(v[8 + i] - bf2f(g));
            }
            *reinterpret_cast<bf16x8*>(&Ah[sr * BKp + sko])     = h0;
            *reinterpret_cast<bf16x8*>(&Ah[sr * BKp + sko + 8]) = h1;
            *reinterpret_cast<bf16x8*>(&Al[sr * BKp + sko])     = l0;
            *reinterpret_cast<bf16x8*>(&Al[sr * BKp + sko + 8]) = l1;
        } else {
            size_t ga = (size_t)(row0 + sr) * 128 + ks * 32 + sko;
            *reinterpret_cast<bf16x8*>(&Ah[sr * BKp + sko])     = *reinterpret_cast<const bf16x8*>(&Xh[ga]);
            *reinterpret_cast<bf16x8*>(&Ah[sr * BKp + sko + 8]) = *reinterpret_cast<const bf16x8*>(&Xh[ga + 8]);
            *reinterpret_cast<bf16x8*>(&Al[sr * BKp + sko])     = *reinterpret_cast<const bf16x8*>(&Xl[ga]);
            *reinterpret_cast<bf16x8*>(&Al[sr * BKp + sko + 8]) = *reinterpret_cast<const bf16x8*>(&Xl[ga + 8]);
        }
        if (BN == 128 || tid < 128) {
            size_t gb = (size_t)sr * 128 + ks * 32 + sko;
            *reinterpret_cast<bf16x8*>(&Bh[sr * BKp + sko])     = *reinterpret_cast<const bf16x8*>(&WhT[gb]);
            *reinterpret_cast<bf16x8*>(&Bh[sr * BKp + sko + 8]) = *reinterpret_cast<const bf16x8*>(&WhT[gb + 8]);
            *reinterpret_cast<bf16x8*>(&Bl[sr * BKp + sko])     = *reinterpret_cast<const bf16x8*>(&WlT[gb]);
            *reinterpret_cast<bf16x8*>(&Bl[sr * BKp + sko + 8]) = *reinterpret_cast<const bf16x8*>(&WlT[gb + 8]);
        }
        __syncthreads();

        bf16x8 bh[NFR], bl[NFR];
        #pragma unroll
        for (int n = 0; n < NFR; ++n) {
            bh[n] = *reinterpret_cast<const bf16x8*>(&Bh[(wn0 + n * 16 + lr) * BKp + lg * 8]);
            bl[n] = *reinterpret_cast<const bf16x8*>(&Bl[(wn0 + n * 16 + lr) * BKp + lg * 8]);
        }
        __builtin_amdgcn_s_setprio(1);           // T5: favor MFMA waves vs count waves
        #pragma unroll
        for (int m = 0; m < MFR; ++m) {
            bf16x8 ah = *reinterpret_cast<const bf16x8*>(&Ah[(wm0 + m * 16 + lr) * BKp + lg * 8]);
            bf16x8 al = *reinterpret_cast<const bf16x8*>(&Al[(wm0 + m * 16 + lr) * BKp + lg * 8]);
            #pragma unroll
            for (int n = 0; n < NFR; ++n) {
                acc[m][n] = __builtin_amdgcn_mfma_f32_16x16x32_bf16(ah, bh[n], acc[m][n], 0, 0, 0);
                acc[m][n] = __builtin_amdgcn_mfma_f32_16x16x32_bf16(ah, bl[n], acc[m][n], 0, 0, 0);
                acc[m][n] = __builtin_amdgcn_mfma_f32_16x16x32_bf16(al, bh[n], acc[m][n], 0, 0, 0);
            }
        }
        __builtin_amdgcn_s_setprio(0);
        __syncthreads();
    }

    // C/D layout: col=lane&15, row=(lane>>4)*4+j  [m89]
    #pragma unroll
    for (int m = 0; m < MFR; ++m)
        #pragma unroll
        for (int n = 0; n < NFR; ++n) {
            int col = wn0 + n * 16 + lr;
            int rb = row0 + wm0 + m * 16 + lg * 4;
            #pragma unroll
            for (int j = 0; j < 4; ++j)
                Y[(size_t)(rb + j) * CW + col] = (short)f2bf(acc[m][n][j]);
        }
}

// ---------------- phase 1: count(2-edge) || gemm1(4 rel, inline conv) || bsum ----------------
__global__ __launch_bounds__(256)
void phase1_kernel(const int* __restrict__ src, const int* __restrict__ dst,
                   unsigned* __restrict__ deg, unsigned* __restrict__ slot,
                   const float* __restrict__ X,
                   const short* __restrict__ w1h, const short* __restrict__ w1l,
                   short* __restrict__ Y,
                   const float* __restrict__ b1, const float* __restrict__ b2,
                   float* __restrict__ bs1, float* __restrict__ bs2)
{
    int bid = blockIdx.x, tid = threadIdx.x;
    if (bid < PAIR1) {
        int sub = bid >> 1;
        if (bid & 1) {
            int rel = sub & 3, rowblk = sub >> 2;
            gemm_body<128, true>(nullptr, nullptr, X, w1h, w1l, Y, 512, rowblk, rel);
        } else {
            count_body2(sub, tid, src, dst, deg, slot);
        }
    } else {
        int t = bid - PAIR1;
        if (t < CB2 - GB1) count_body2(GB1 + t, tid, src, dst, deg, slot);
        else              bsum_body(tid, b1, b2, bs1, bs2);
    }
}

// standalone count / bsum (path B)
__global__ __launch_bounds__(256)
void count_kernel(const int* __restrict__ src, const int* __restrict__ dst,
                  unsigned* __restrict__ deg, unsigned* __restrict__ slot)
{
    count_body2(blockIdx.x, threadIdx.x, src, dst, deg, slot);
}

__global__ void bsum_kernel(const float* __restrict__ b1, const float* __restrict__ b2,
                            float* __restrict__ bs1, float* __restrict__ bs2)
{
    bsum_body(threadIdx.x, b1, b2, bs1, bs2);
}

// ---------------- norms fused into scan pass 1 ----------------
__global__ __launch_bounds__(256)
void norms_scan1_kernel(const unsigned* __restrict__ deg, float* __restrict__ nrm,
                        uint2* __restrict__ rpnd, unsigned* __restrict__ partial)
{
    __shared__ unsigned s[256];
    int b = blockIdx.x, t = threadIdx.x;
    int start = b * CH;
    int n = TOT - start; if (n > CH) n = CH;
    unsigned sum = 0;
    for (int i = t; i < n; i += 256) {
        unsigned sd = deg[start + i];
        unsigned dd = deg[TOT + start + i];
        nrm[start + i] = rsqrtf((float)(sd > 0u ? sd : 1u));
        rpnd[start + i].y = __builtin_bit_cast(unsigned, rsqrtf((float)(dd > 0u ? dd : 1u)));
        sum += dd;
    }
    s[t] = sum; __syncthreads();
    for (int d = 128; d > 0; d >>= 1) {
        if (t < d) s[t] += s[t + d];
        __syncthreads();
    }
    if (t == 0) partial[b] = s[0];
}

__global__ __launch_bounds__(1024)
void scan2_kernel(unsigned* __restrict__ partial, unsigned* __restrict__ rowptr)
{
    __shared__ unsigned s[NB1];
    int t = threadIdx.x;
    unsigned orig = partial[t];
    s[t] = orig; __syncthreads();
    for (int d = 1; d < NB1; d <<= 1) {
        unsigned v = (t >= d) ? s[t - d] : 0u;
        __syncthreads();
        s[t] += v;
        __syncthreads();
    }
    partial[t] = s[t] - orig;
    if (t == 0) rowptr[TOT] = (unsigned)RE;
}

__global__ __launch_bounds__(256)
void scan3_kernel(const unsigned* __restrict__ deg, const unsigned* __restrict__ base,
                  unsigned* __restrict__ rowptr, uint2* __restrict__ rpnd)
{
    __shared__ unsigned s[CH];
    int b = blockIdx.x, t = threadIdx.x;
    int start = b * CH;
    int n = TOT - start; if (n > CH) n = CH;
    if (n <= 0) return;
    for (int i = t; i < n; i += 256) s[i] = deg[TOT + start + i];
    __syncthreads();
    if (t == 0) {
        unsigned run = base[b];
        for (int i = 0; i < n; ++i) { unsigned v = s[i]; s[i] = run; run += v; }
    }
    __syncthreads();
    for (int i = t; i < n; i += 256) {
        unsigned v = s[i];
        rowptr[start + i] = v;
        rpnd[start + i].x = v;
    }
}

// atomic-free CSR fill: pos = rowptr + slot (4 edges/thread)
__global__ __launch_bounds__(256)
void fill_csr_kernel(const int* __restrict__ src, const int* __restrict__ dst,
                     const unsigned* __restrict__ slot, const uint2* __restrict__ rpnd,
                     const float* __restrict__ nrm, int2* __restrict__ csrw)
{
    int e0 = (blockIdx.x * 256 + threadIdx.x) * 4;
    if (e0 >= RE) return;
    int r = (unsigned)e0 / (unsigned)Ee;
    int base = r * Nn;
    int4 s4 = *reinterpret_cast<const int4*>(src + e0);
    int4 d4 = *reinterpret_cast<const int4*>(dst + e0);
    uint4 sl = *reinterpret_cast<const uint4*>(slot + e0);
    #pragma unroll
    for (int i = 0; i < 4; ++i) {
        int s = (i == 0) ? s4.x : (i == 1) ? s4.y : (i == 2) ? s4.z : s4.w;
        int d = (i == 0) ? d4.x : (i == 1) ? d4.y : (i == 2) ? d4.z : d4.w;
        unsigned k = (i == 0) ? sl.x : (i == 1) ? sl.y : (i == 2) ? sl.z : sl.w;
        uint2 rn = rpnd[base + d];
        float w = nrm[base + s] * __builtin_bit_cast(float, rn.y);
        int2 v; v.x = s; v.y = __builtin_bit_cast(int, w);
        csrw[rn.x + k] = v;
    }
}

// convert W1/W2 to transposed hi/lo bf16
__global__ __launch_bounds__(256)
void convw_kernel(const float* __restrict__ W1, const float* __restrict__ W2,
                  short* __restrict__ w1h, short* __restrict__ w1l,
                  short* __restrict__ w2h, short* __restrict__ w2l)
{
    int gid = blockIdx.x * 256 + threadIdx.x;
    if (gid < 4 * 128 * 128) {
        int r = gid >> 14, rem = gid & 16383, n = rem >> 7, k = rem & 127;
        float v = W1[(r << 14) + k * 128 + n];
        unsigned short h = f2bf(v);
        unsigned short l = f2bf(v - bf2f(h));
        w1h[(r << 14) + n * 128 + k] = (short)h;
        w1l[(r << 14) + n * 128 + k] = (short)l;
    } else {
        int g2 = gid - 65536;
        if (g2 >= 4 * 64 * 128) return;
        int r = g2 >> 13, rem = g2 & 8191, n = rem >> 7, k = rem & 127;
        float v = W2[(r << 13) + k * 64 + n];
        unsigned short h = f2bf(v);
        unsigned short l = f2bf(v - bf2f(h));
        w2h[(r << 13) + n * 128 + k] = (short)h;
        w2l[(r << 13) + n * 128 + k] = (short)l;
    }
}

// standalone GEMM: blockIdx.y = relation
template<int BN, bool CONVA>
__global__ __launch_bounds__(256)
void gemm_kernel(const short* __restrict__ Xh, const short* __restrict__ Xl,
                 const float* __restrict__ Xf,
                 const short* __restrict__ WhT_, const short* __restrict__ WlT_,
                 short* __restrict__ Y_, int CW)
{
    gemm_body<BN, CONVA>(Xh, Xl, Xf, WhT_, WlT_, Y_, CW, blockIdx.x, blockIdx.y);
}

// ---------------- paired-edge CSR gather over NR relations (Y bf16) ----------------
template<int F, int NR>
__global__ __launch_bounds__(256)
void gather_kernel(const short* __restrict__ Y, const unsigned* __restrict__ rowptr,
                   const int2* __restrict__ csrw, const float* __restrict__ bsum,
                   float* __restrict__ H, short* __restrict__ Xh, short* __restrict__ Xl,
                   int CW, int accumulate, int finalize)
{
    constexpr int FL = F / 32;               // 4 (F=128) or 2 (F=64)
    int wid = (blockIdx.x * 256 + threadIdx.x) >> 6;
    int lane = threadIdx.x & 63;
    int half = lane >> 5, li = lane & 31;
    if (wid >= Nn) return;

    float t[FL];
    #pragma unroll
    for (int f = 0; f < FL; ++f) t[f] = 0.f;

    #pragma unroll
    for (int rl = 0; rl < NR; ++rl) {
        const short* yr = Y + rl * F;
        unsigned e  = rowptr[rl * Nn + wid];
        unsigned e1 = rowptr[rl * Nn + wid + 1];
        for (; e + 4 <= e1; e += 4) {
            int2 a0 = csrw[e + half];
            int2 a1 = csrw[e + 2 + half];
            float w0 = __builtin_bit_cast(float, a0.y);
            float w1 = __builtin_bit_cast(float, a1.y);
            if constexpr (FL == 4) {
                uint2 p0 = *reinterpret_cast<const uint2*>(yr + (size_t)a0.x * CW + li * 4);
                uint2 p1 = *reinterpret_cast<const uint2*>(yr + (size_t)a1.x * CW + li * 4);
                t[0] += w0 * bfbits_lo(p0.x) + w1 * bfbits_lo(p1.x);
                t[1] += w0 * bfbits_hi(p0.x) + w1 * bfbits_hi(p1.x);
                t[2] += w0 * bfbits_lo(p0.y) + w1 * bfbits_lo(p1.y);
                t[3] += w0 * bfbits_hi(p0.y) + w1 * bfbits_hi(p1.y);
            } else {
                unsigned p0 = *reinterpret_cast<const unsigned*>(yr + (size_t)a0.x * CW + li * 2);
                unsigned p1 = *reinterpret_cast<const unsigned*>(yr + (size_t)a1.x * CW + li * 2);
                t[0] += w0 * bfbits_lo(p0) + w1 * bfbits_lo(p1);
                t[1] += w0 * bfbits_hi(p0) + w1 * bfbits_hi(p1);
            }
        }
        if (e + 2 <= e1) {
            int2 a = csrw[e + half];
            float w = __builtin_bit_cast(float, a.y);
            if constexpr (FL == 4) {
                uint2 p = *reinterpret_cast<const uint2*>(yr + (size_t)a.x * CW + li * 4);
                t[0] += w * bfbits_lo(p.x); t[1] += w * bfbits_hi(p.x);
                t[2] += w * bfbits_lo(p.y); t[3] += w * bfbits_hi(p.y);
            } else {
                unsigned p = *reinterpret_cast<const unsigned*>(yr + (size_t)a.x * CW + li * 2);
                t[0] += w * bfbits_lo(p); t[1] += w * bfbits_hi(p);
            }
            e += 2;
        }
        if (e < e1 && half == 0) {
            int2 a = csrw[e];
            float w = __builtin_bit_cast(float, a.y);
            if constexpr (FL == 4) {
                uint2 p = *reinterpret_cast<const uint2*>(yr + (size_t)a.x * CW + li * 4);
                t[0] += w * bfbits_lo(p.x); t[1] += w * bfbits_hi(p.x);
                t[2] += w * bfbits_lo(p.y); t[3] += w * bfbits_hi(p.y);
            } else {
                unsigned p = *reinterpret_cast<const unsigned*>(yr + (size_t)a.x * CW + li * 2);
                t[0] += w * bfbits_lo(p); t[1] += w * bfbits_hi(p);
            }
        }
    }

    #pragma unroll
    for (int f = 0; f < FL; ++f) t[f] += __shfl_xor(t[f], 32, 64);

    if (half != 0) return;
    float* hp = H + (size_t)wid * F + li * FL;
    if (accumulate) {
        #pragma unroll
        for (int f = 0; f < FL; ++f) t[f] += hp[f];
    } else {
        #pragma unroll
        for (int f = 0; f < FL; ++f) t[f] += bsum[li * FL + f];
    }
    if (F == 128 && finalize) {
        short4 hv, lv;
        #pragma unroll
        for (int f = 0; f < 4; ++f) {
            float v = fmaxf(t[f], 0.f);
            unsigned short hb = f2bf(v);
            ((short*)&hv)[f] = (short)hb;
            ((short*)&lv)[f] = (short)f2bf(v - bf2f(hb));
        }
        *reinterpret_cast<short4*>(Xh + (size_t)wid * F + li * 4) = hv;
        *reinterpret_cast<short4*>(Xl + (size_t)wid * F + li * 4) = lv;
    } else {
        if constexpr (FL == 4) {
            *reinterpret_cast<float4*>(hp) = make_float4(t[0], t[1], t[2], t[3]);
        } else {
            *reinterpret_cast<float2*>(hp) = make_float2(t[0], t[1]);
        }
    }
}

extern "C" void kernel_launch(void* const* d_in, const int* in_sizes, int n_in,
                              void* d_out, int out_size, void* d_ws, size_t ws_size,
                              hipStream_t stream)
{
    const float* x  = (const float*)d_in[0];
    const int* esrc = (const int*)d_in[1];
    const int* edst = (const int*)d_in[2];
    const float* W1 = (const float*)d_in[3];
    const float* b1 = (const float*)d_in[4];
    const float* W2 = (const float*)d_in[5];
    const float* b2 = (const float*)d_in[6];
    float* out = (float*)d_out;

    // ---- workspace layout ----
    char* ws = (char*)d_ws;
    size_t off = 0;
    auto alloc = [&](size_t bytes) { char* p = ws + off; off += (bytes + 255) & ~(size_t)255; return p; };
    unsigned* deg     = (unsigned*)alloc((size_t)2 * TOT * 4);
    float*    nrm     = (float*)   alloc((size_t)TOT * 4);          // nsrc
    uint2*    rpnd    = (uint2*)   alloc((size_t)TOT * 8);          // {rowptr, ndst}
    unsigned* rowptr  = (unsigned*)alloc((size_t)(TOT + 1) * 4);
    unsigned* partial = (unsigned*)alloc((size_t)NB1 * 4);
    unsigned* slot    = (unsigned*)alloc((size_t)RE * 4);
    float*    bs1     = (float*)   alloc(128 * 4);
    float*    bs2     = (float*)   alloc(64 * 4);
    short*    w1h     = (short*)   alloc((size_t)4 * 128 * 128 * 2);
    short*    w1l     = (short*)   alloc((size_t)4 * 128 * 128 * 2);
    short*    w2h     = (short*)   alloc((size_t)4 * 64 * 128 * 2);
    short*    w2l     = (short*)   alloc((size_t)4 * 64 * 128 * 2);
    int2*     csrw    = (int2*)    alloc((size_t)RE * 8);
    short*    xh      = (short*)   alloc((size_t)NP * 128 * 2);
    short*    xl      = (short*)   alloc((size_t)NP * 128 * 2);

    size_t yslot = (size_t)NP * 128 * 2;          // 25.6MB (bf16, 128 cols)
    bool pathA = (ws_size >= off + 4 * yslot + 4096);
    float* h = nullptr;
    short* Y;
    if (pathA) {
        Y = (short*)alloc(4 * yslot);
    } else {
        h = (float*)alloc((size_t)NP * 128 * 4);
        Y = (short*)alloc(yslot);
    }

    const int ggrid = (Nn * 64 + 255) / 256;      // one wave per dst node

    // ---- phase 0: weight conversion (tiny, independent) ----
    convw_kernel<<<384, 256, 0, stream>>>(W1, W2, w1h, w1l, w2h, w2l);
    hipMemsetAsync(deg, 0, (size_t)2 * TOT * 4, stream);

    if (pathA) {
        // ---- phase 1: count(2-edge) || gemm1(4 rel, inline x conv) || bsum ----
        phase1_kernel<<<P1_GRID, 256, 0, stream>>>(
            esrc, edst, deg, slot, x, w1h, w1l, Y, b1, b2, bs1, bs2);
        // ---- phase 2: norms+scan ----
        norms_scan1_kernel<<<NB1, 256, 0, stream>>>(deg, nrm, rpnd, partial);
        scan2_kernel<<<1, NB1, 0, stream>>>(partial, rowptr);
        scan3_kernel<<<NB1, 256, 0, stream>>>(deg, partial, rowptr, rpnd);
        // ---- phase 3: fill ----
        fill_csr_kernel<<<FB, 256, 0, stream>>>(esrc, edst, slot, rpnd, nrm, csrw);
        // ---- phase 4: layer-1 gather (finalize: bias+ReLU+split into xh/xl) ----
        gather_kernel<128, 4><<<ggrid, 256, 0, stream>>>(
            Y, rowptr, csrw, bs1, out /*unused*/, xh, xl, 512, 0, 1);
        // ---- phase 5: layer-2 GEMM + gather ----
        gemm_kernel<64, false><<<dim3(NPB, 4), 256, 0, stream>>>(
            xh, xl, nullptr, w2h, w2l, Y, 256);
        gather_kernel<64, 4><<<ggrid, 256, 0, stream>>>(
            Y, rowptr, csrw, bs2, out, nullptr, nullptr, 256, 0, 0);
    } else {
        count_kernel<<<CB2, 256, 0, stream>>>(esrc, edst, deg, slot);
        bsum_kernel<<<1, 128, 0, stream>>>(b1, b2, bs1, bs2);
        norms_scan1_kernel<<<NB1, 256, 0, stream>>>(deg, nrm, rpnd, partial);
        scan2_kernel<<<1, NB1, 0, stream>>>(partial, rowptr);
        scan3_kernel<<<NB1, 256, 0, stream>>>(deg, partial, rowptr, rpnd);
        fill_csr_kernel<<<FB, 256, 0, stream>>>(esrc, edst, slot, rpnd, nrm, csrw);
        for (int r = 0; r < Rr; ++r) {
            gemm_kernel<128, true><<<dim3(NPB, 1), 256, 0, stream>>>(
                nullptr, nullptr, x, w1h + (size_t)r * 128 * 128, w1l + (size_t)r * 128 * 128, Y, 128);
            gather_kernel<128, 1><<<ggrid, 256, 0, stream>>>(
                Y, rowptr + (size_t)r * Nn, csrw, bs1, h, xh, xl, 128, r > 0, r == Rr - 1);
        }
        for (int r = 0; r < Rr; ++r) {
            gemm_kernel<64, false><<<dim3(NPB, 1), 256, 0, stream>>>(
                xh, xl, nullptr, w2h + (size_t)r * 64 * 128, w2l + (size_t)r * 64 * 128, Y, 64);
            gather_kernel<64, 1><<<ggrid, 256, 0, stream>>>(
                Y, rowptr + (size_t)r * Nn, csrw, bs2, out, nullptr, nullptr, 64, r > 0, 0);
        }
    }
}